// Round 22
// baseline (122.309 us; speedup 1.0000x reference)
//
#include <hip/hip_runtime.h>

#define SEQ 2048
#define BATCH 2
#define DM 1024
#define NH 16
#define DK 64
#define BH (BATCH*NH)

typedef __attribute__((ext_vector_type(8))) short bf16x8;
typedef __attribute__((ext_vector_type(4))) float f32x4;

__device__ __forceinline__ ushort f2bf(float f) {
  union { float f; unsigned u; } v; v.f = f;
  unsigned r = (v.u + 0x7fffu + ((v.u >> 16) & 1u)) >> 16;
  return (ushort)r;
}
__device__ __forceinline__ float bf2f(ushort h) {
  union { unsigned u; float f; } v; v.u = ((unsigned)h) << 16;
  return v.f;
}
__device__ __forceinline__ unsigned cvtpk(float lo, float hi) {
  unsigned r;
  asm("v_cvt_pk_bf16_f32 %0, %1, %2" : "=v"(r) : "v"(lo), "v"(hi));
  return r;
}

// counted-vmcnt sync primitives (T4)
#define WAITV4 asm volatile("s_waitcnt vmcnt(4)" ::: "memory")
#define WAITV3 asm volatile("s_waitcnt vmcnt(3)" ::: "memory")
#define WAITV0 asm volatile("s_waitcnt vmcnt(0)" ::: "memory")
#define WAITL0 asm volatile("s_waitcnt lgkmcnt(0)" ::: "memory")
#define BARR() __builtin_amdgcn_s_barrier()

// ---------------- fused prep: X-cast (z<3), W-cast (z3..6), RoPE table -------
struct P8 { const float* p[7]; };
__global__ void k_prep(P8 in, ushort* __restrict__ xout, ushort* __restrict__ wout,
                       float* __restrict__ tab) {
  const int z = blockIdx.z;
  const float* src = in.p[z];
  ushort* dst;
  int n4;
  if (z < 3) {
    dst = xout + (size_t)z * (BATCH * SEQ * DM);
    n4 = BATCH * SEQ * DM / 4;
  } else {
    dst = wout + (size_t)(z - 3) * (DM * DM);
    n4 = DM * DM / 4;
  }
  int i = blockIdx.x * blockDim.x + threadIdx.x;
  int st = gridDim.x * blockDim.x;
  for (; i < n4; i += st) {
    float4 v = reinterpret_cast<const float4*>(src)[i];
    ushort4 o;
    o.x = f2bf(v.x); o.y = f2bf(v.y); o.z = f2bf(v.z); o.w = f2bf(v.w);
    reinterpret_cast<ushort4*>(dst)[i] = o;
  }
  if (z == 3 && blockIdx.x < 256) {
    int id = blockIdx.x * 256 + threadIdx.x;   // < 65536 = SEQ*32
    int s = id >> 5, ii = id & 31;
    float inv = powf(10000.f, -(float)ii / 32.f);
    float ang = (float)s * inv;
    float sn, cs;
    sincosf(ang, &sn, &cs);
    tab[id * 2] = cs;
    tab[id * 2 + 1] = sn;
  }
}

// ---------------- async global->LDS 16B ----------------
__device__ __forceinline__ void gll16(const void* g, void* l) {
  __builtin_amdgcn_global_load_lds((const __attribute__((address_space(1))) void*)g,
                                   (__attribute__((address_space(3))) void*)l, 16, 0, 0);
}

// chunk-XOR swizzled fragment read: row stride 64 B (32 bf16)
#define AFRAG(AS_, row_)                                                       \
  (*(const bf16x8*)((const char*)(AS_) + (row_) * 64 + ((((l4) ^ (((row_) >> 1) & 3)) & 3) * 16)))

// ---------------- QKV GEMM: 256x128 tile, 8 waves, BK=32, 2-phase ------------
// 384 blocks (16 M x 8 N x 3 z) -> full CU coverage + 2 blocks co-resident on
// half the CUs (LDS 48 KB, 3 fit) so barrier stalls overlap across blocks.
// Stage = 3 gll16/thread (A: 2, B: 1); counted WAITV3 as in k_gemm_f.
#define GSTAGE(AD, BD, kk_) do {                                               \
    _Pragma("unroll")                                                          \
    for (int i_ = 0; i_ < 2; ++i_) {                                           \
      int tt_ = i_ * 512 + tid;                                                \
      int row_ = tt_ >> 2, c_ = (tt_ & 3) ^ ((row_ >> 1) & 3);                 \
      gll16(Abase + (size_t)row_ * K + (kk_) + c_ * 8,                         \
            (void*)((char*)(AD) + tt_ * 16));                                  \
    }                                                                          \
    {                                                                          \
      int row_ = tid >> 2, c_ = (tid & 3) ^ ((row_ >> 1) & 3);                 \
      gll16(Bbase + (size_t)row_ * K + (kk_) + c_ * 8,                         \
            (void*)((char*)(BD) + tid * 16));                                  \
    }                                                                          \
  } while (0)

#define GCOMP(AS_, BS_) do {                                                   \
    bf16x8 af[8], bfr[2];                                                      \
    _Pragma("unroll")                                                          \
    for (int i = 0; i < 8; ++i) af[i] = AFRAG(AS_, wr * 128 + i * 16 + l15);   \
    _Pragma("unroll")                                                          \
    for (int i = 0; i < 2; ++i) bfr[i] = AFRAG(BS_, wc * 32 + i * 16 + l15);   \
    __builtin_amdgcn_s_setprio(1);                                             \
    _Pragma("unroll")                                                          \
    for (int mi = 0; mi < 8; ++mi)                                             \
      _Pragma("unroll")                                                        \
      for (int ni = 0; ni < 2; ++ni)                                           \
        acc[mi][ni] = __builtin_amdgcn_mfma_f32_16x16x32_bf16(af[mi], bfr[ni], acc[mi][ni], 0, 0, 0); \
    __builtin_amdgcn_s_setprio(0);                                             \
  } while (0)

// grid: flat 384 = 8(mlo) x 8(nb) x 2(mhi) x 3(z); id%8==mlo -> XCD-local A.
__global__ __launch_bounds__(512) void k_gemm_qkv(const ushort* __restrict__ A0,
                                                  const ushort* __restrict__ Bw0,
                                                  ushort* __restrict__ qT,
                                                  ushort* __restrict__ kT,
                                                  ushort* __restrict__ vT,
                                                  const float* __restrict__ tab,
                                                  float qscale, int M, int N, int K) {
  const int id = blockIdx.x;
  const int mlo = id & 7, nb = (id >> 3) & 7, mhi = (id >> 6) & 1, z = id >> 7;
  const int m0 = (mhi * 8 + mlo) * 256, n0 = nb * 128;
  const ushort* Abase = A0 + (size_t)z * ((size_t)M * K) + (size_t)m0 * K;
  const ushort* Bbase = Bw0 + (size_t)z * ((size_t)N * K) + (size_t)n0 * K;
  __shared__ ushort As0[256 * 32], As1[256 * 32];   // 16 KB each
  __shared__ ushort Bs0[128 * 32], Bs1[128 * 32];   // 8 KB each -> 48 KB total
  const int tid = threadIdx.x;
  const int w = tid >> 6, lane = tid & 63;
  const int l15 = lane & 15, l4 = lane >> 4;
  const int wr = w >> 2, wc = w & 3;       // 2 x 4 waves -> per-wave 128 x 32
  f32x4 acc[8][2] = {};
  GSTAGE(As0, Bs0, 0);
  GSTAGE(As1, Bs1, 32);
  for (int kk = 0; kk < K - 64; kk += 64) {
    WAITV3; BARR();
    GCOMP(As0, Bs0);
    WAITL0; BARR();
    GSTAGE(As0, Bs0, kk + 64);
    WAITV3; BARR();
    GCOMP(As1, Bs1);
    WAITL0; BARR();
    if (kk + 96 < K) GSTAGE(As1, Bs1, kk + 96);
  }
  WAITV3; BARR();
  GCOMP(As0, Bs0);
  WAITV0; BARR();
  GCOMP(As1, Bs1);
  // epilogues
  if (z == 2) {
#pragma unroll
    for (int mi = 0; mi < 8; ++mi)
#pragma unroll
      for (int ni = 0; ni < 2; ++ni) {
        int row = m0 + wr * 128 + mi * 16 + l4 * 4;
        int col = n0 + wc * 32 + ni * 16 + l15;
        int bh2 = (row >> 11) * 16 + (col >> 6);
        int d = col & 63, s = row & (SEQ - 1);
        uint2 pk;
        pk.x = cvtpk(acc[mi][ni][0], acc[mi][ni][1]);
        pk.y = cvtpk(acc[mi][ni][2], acc[mi][ni][3]);
        *(uint2*)(vT + ((size_t)bh2 * 64 + d) * SEQ + s) = pk;
      }
  } else {
    const float scale = (z == 0) ? qscale : 1.0f;
    ushort* T = (z == 0) ? qT : kT;
    const bool odd = (l15 & 1);
#pragma unroll
    for (int mi = 0; mi < 8; ++mi)
#pragma unroll
      for (int ni = 0; ni < 2; ++ni)
#pragma unroll
        for (int r = 0; r < 4; ++r) {
          int row = m0 + wr * 128 + mi * 16 + l4 * 4 + r;
          int col = n0 + wc * 32 + ni * 16 + l15;
          float v = acc[mi][ni][r];
          float pv = __shfl_xor(v, 1);
          int s = row & (SEQ - 1);
          int d = col & 63;
          float2 cs = *(const float2*)(tab + ((size_t)s * 32 + (d >> 1)) * 2);
          float xe = odd ? pv : v, xo = odd ? v : pv;
          float outv = (odd ? (xe * cs.y + xo * cs.x) : (xe * cs.x - xo * cs.y)) * scale;
          int bh2 = (row >> 11) * 16 + (col >> 6);
          T[((size_t)bh2 * SEQ + s) * 64 + d] = f2bf(outv);
        }
  }
}

// ---------------- final GEMM: counted-vmcnt 2-deep pipeline, fp32 out --------
#define FSTAGE(AD, BD, kk_) do {                                               \
    gll16(A + (size_t)(m0 + srow) * K + (kk_) + scol, (void*)((AD) + w * 512));\
    gll16(Bw + (size_t)(n0 + srow) * K + (kk_) + scol, (void*)((BD) + w * 512));\
    gll16(Bw + (size_t)(n0 + 64 + srow) * K + (kk_) + scol, (void*)((BD) + 2048 + w * 512)); \
  } while (0)

#define FCOMP(AS_, BS_) do {                                                   \
    bf16x8 aff[2], bff[4];                                                     \
    _Pragma("unroll")                                                          \
    for (int i = 0; i < 2; ++i)                                                \
      aff[i] = *(const bf16x8*)((AS_) + (wr * 32 + i * 16 + l15) * 32 + l4 * 8);\
    _Pragma("unroll")                                                          \
    for (int i = 0; i < 4; ++i)                                                \
      bff[i] = *(const bf16x8*)((BS_) + (wc * 64 + i * 16 + l15) * 32 + l4 * 8);\
    _Pragma("unroll")                                                          \
    for (int mi = 0; mi < 2; ++mi)                                             \
      _Pragma("unroll")                                                        \
      for (int ni = 0; ni < 4; ++ni)                                           \
        acc[mi][ni] = __builtin_amdgcn_mfma_f32_16x16x32_bf16(aff[mi], bff[ni], acc[mi][ni], 0, 0, 0); \
  } while (0)

__global__ __launch_bounds__(256) void k_gemm_f(const ushort* __restrict__ A,
                                                const ushort* __restrict__ Bw,
                                                float* __restrict__ C, int M, int N, int K) {
  const int id = blockIdx.x;
  const int mlo = id & 7, nb = (id >> 3) & 7, mhi = id >> 6;
  const int m0 = (mhi * 8 + mlo) * 64, n0 = nb * 128;
  __shared__ ushort As0[64 * 32], Bs0[128 * 32];
  __shared__ ushort As1[64 * 32], Bs1[128 * 32];
  const int tid = threadIdx.x;
  const int w = tid >> 6, lane = tid & 63;
  const int l15 = lane & 15, l4 = lane >> 4;
  const int wr = w >> 1, wc = w & 1;
  const int srow = tid >> 2, scol = (tid & 3) * 8;
  f32x4 acc[2][4] = {};
  FSTAGE(As0, Bs0, 0);
  FSTAGE(As1, Bs1, 32);
  for (int kk = 0; kk < K - 64; kk += 64) {
    WAITV3; BARR();
    FCOMP(As0, Bs0);
    WAITL0; BARR();
    FSTAGE(As0, Bs0, kk + 64);
    WAITV3; BARR();
    FCOMP(As1, Bs1);
    WAITL0; BARR();
    if (kk + 96 < K) FSTAGE(As1, Bs1, kk + 96);
  }
  WAITV3; BARR();
  FCOMP(As0, Bs0);
  WAITV0; BARR();
  FCOMP(As1, Bs1);
#pragma unroll
  for (int mi = 0; mi < 2; ++mi)
#pragma unroll
    for (int ni = 0; ni < 4; ++ni)
#pragma unroll
      for (int r = 0; r < 4; ++r) {
        int row = m0 + wr * 32 + mi * 16 + l4 * 4 + r;
        int col = n0 + wc * 64 + ni * 16 + l15;
        C[(size_t)row * N + col] = acc[mi][ni][r];
      }
}

// ---------------- causal flash attention: QBLK=128, KVBLK=128 ----------------
#define KSTAGE(DST, kt_) do {                                                  \
    const ushort* kb_ = kT + hb + (size_t)(kt_) * 8192;                        \
    _Pragma("unroll")                                                          \
    for (int i_ = 0; i_ < 4; ++i_) {                                           \
      int tt_ = i_ * 256 + tid;                                                \
      int row_ = tt_ >> 3, c_ = (tt_ & 7) ^ (row_ & 7);                        \
      gll16(kb_ + (size_t)row_ * 64 + c_ * 8,                                  \
            (void*)((char*)(DST) + (i_ * 256 + w * 64) * 16));                 \
    }                                                                          \
  } while (0)

#define VSTAGE(DST, kt_) do {                                                  \
    const ushort* vb_ = vT + vbase + (size_t)(kt_) * 128;                      \
    _Pragma("unroll")                                                          \
    for (int i_ = 0; i_ < 4; ++i_) {                                           \
      int tt_ = i_ * 256 + tid;                                                \
      int row_ = tt_ >> 4, c_ = (tt_ & 15) ^ (row_ & 15);                      \
      gll16(vb_ + (size_t)row_ * SEQ + c_ * 8,                                 \
            (void*)((char*)(DST) + (i_ * 256 + w * 64) * 16));                 \
    }                                                                          \
  } while (0)

#define FRK(BASE, row_, cidx)                                                  \
  (*(const bf16x8*)((const char*)(BASE) + (row_) * 128 + ((((cidx) ^ ((row_) & 7)) & 7) * 16)))
#define FRV(BASE, row_, cidx)                                                  \
  (*(const bf16x8*)((const char*)(BASE) + (row_) * 256 + ((((cidx) ^ ((row_) & 15)) & 15) * 16)))

#define SMAX8(P, MRUN, LRUN, ACC) do {                                         \
    float mx = P[0][0];                                                        \
    _Pragma("unroll")                                                          \
    for (int nf = 0; nf < 8; ++nf)                                             \
      _Pragma("unroll")                                                        \
      for (int r = 0; r < 4; ++r) mx = fmaxf(mx, P[nf][r]);                    \
    mx = fmaxf(mx, __shfl_xor(mx, 16));                                        \
    mx = fmaxf(mx, __shfl_xor(mx, 32));                                        \
    if (!__all(mx <= MRUN)) {                                                  \
      const float mn = fmaxf(MRUN, mx);                                        \
      const float so = __builtin_amdgcn_exp2f(MRUN - mn);                      \
      float soq[4];                                                            \
      _Pragma("unroll")                                                        \
      for (int r = 0; r < 4; ++r) soq[r] = __shfl(so, l4 * 4 + r);             \
      _Pragma("unroll")                                                        \
      for (int df = 0; df < 4; ++df)                                           \
        _Pragma("unroll")                                                      \
        for (int r = 0; r < 4; ++r) ACC[df][r] *= soq[r];                      \
      LRUN *= so;                                                              \
      MRUN = mn;                                                               \
    }                                                                          \
    float rs = 0.f;                                                            \
    _Pragma("unroll")                                                          \
    for (int nf = 0; nf < 8; ++nf) {                                           \
      float e0 = __builtin_amdgcn_exp2f(P[nf][0] - MRUN);                      \
      float e1 = __builtin_amdgcn_exp2f(P[nf][1] - MRUN);                      \
      float e2 = __builtin_amdgcn_exp2f(P[nf][2] - MRUN);                      \
      float e3 = __builtin_amdgcn_exp2f(P[nf][3] - MRUN);                      \
      P[nf][0] = e0; P[nf][1] = e1; P[nf][2] = e2; P[nf][3] = e3;              \
      rs += (e0 + e1) + (e2 + e3);                                             \
    }                                                                          \
    LRUN += rs;                                                                \
  } while (0)

// PV for one 64-k half H, BOTH strips sharing the V-fragment reads.
#define PVBOTH(VC, H, DO0) do {                                                \
    if (DO0) {                                                                 \
      _Pragma("unroll")                                                        \
      for (int i = 0; i < 4; ++i) {                                            \
        uint2 pk;                                                              \
        pk.x = cvtpk(p0[(H) * 4 + i][0], p0[(H) * 4 + i][1]);                  \
        pk.y = cvtpk(p0[(H) * 4 + i][2], p0[(H) * 4 + i][3]);                  \
        *(uint2*)(myP0 + ((l15 * 128 + i * 32 + l4 * 8) ^ swz)) = pk;          \
      }                                                                        \
    }                                                                          \
    _Pragma("unroll")                                                          \
    for (int i = 0; i < 4; ++i) {                                              \
      uint2 pk;                                                                \
      pk.x = cvtpk(p1[(H) * 4 + i][0], p1[(H) * 4 + i][1]);                    \
      pk.y = cvtpk(p1[(H) * 4 + i][2], p1[(H) * 4 + i][3]);                    \
      *(uint2*)(myP1 + ((l15 * 128 + i * 32 + l4 * 8) ^ swz)) = pk;            \
    }                                                                          \
    bf16x8 pa00, pa01;                                                         \
    if (DO0) {                                                                 \
      pa00 = *(const bf16x8*)(myP0 + ((l15 * 128 + l4 * 16) ^ swz));           \
      pa01 = *(const bf16x8*)(myP0 + ((l15 * 128 + 64 + l4 * 16) ^ swz));      \
    }                                                                          \
    const bf16x8 pa10 = *(const bf16x8*)(myP1 + ((l15 * 128 + l4 * 16) ^ swz));\
    const bf16x8 pa11 = *(const bf16x8*)(myP1 + ((l15 * 128 + 64 + l4 * 16) ^ swz));\
    __builtin_amdgcn_s_setprio(1);                                             \
    _Pragma("unroll")                                                          \
    for (int df = 0; df < 4; ++df) {                                           \
      bf16x8 v0_ = FRV(VC, df * 16 + l15, (H) * 8 + l4);                       \
      bf16x8 v1_ = FRV(VC, df * 16 + l15, (H) * 8 + l4 + 4);                   \
      if (DO0) {                                                               \
        acc0[df] = __builtin_amdgcn_mfma_f32_16x16x32_bf16(pa00, v0_, acc0[df], 0, 0, 0); \
        acc0[df] = __builtin_amdgcn_mfma_f32_16x16x32_bf16(pa01, v1_, acc0[df], 0, 0, 0); \
      }                                                                        \
      acc1[df] = __builtin_amdgcn_mfma_f32_16x16x32_bf16(pa10, v0_, acc1[df], 0, 0, 0); \
      acc1[df] = __builtin_amdgcn_mfma_f32_16x16x32_bf16(pa11, v1_, acc1[df], 0, 0, 0); \
    }                                                                          \
    __builtin_amdgcn_s_setprio(0);                                             \
  } while (0)

#define STEP(KC, VC, KN, VN, kt_, DIAG, PREF) do {                             \
    if (PREF) { KSTAGE(KN, (kt_) + 1); VSTAGE(VN, (kt_) + 1); }                \
    float p0[8][4], p1[8][4];                                                  \
    __builtin_amdgcn_s_setprio(1);                                             \
    _Pragma("unroll")                                                          \
    for (int nf = 0; nf < 8; ++nf) {                                           \
      bf16x8 k0_ = FRK(KC, nf * 16 + l15, l4);                                 \
      bf16x8 k1_ = FRK(KC, nf * 16 + l15, l4 + 4);                             \
      if (!(DIAG) || nf < 4) {                                                 \
        f32x4 z = {0.f, 0.f, 0.f, 0.f};                                        \
        z = __builtin_amdgcn_mfma_f32_16x16x32_bf16(k0_, qb00, z, 0, 0, 0);    \
        z = __builtin_amdgcn_mfma_f32_16x16x32_bf16(k1_, qb01, z, 0, 0, 0);    \
        _Pragma("unroll")                                                      \
        for (int r = 0; r < 4; ++r) {                                          \
          float sc = z[r];                                                     \
          if (DIAG && (nf * 16 + l4 * 4 + r) > (w * 16 + l15)) sc = -INFINITY; \
          p0[nf][r] = sc;                                                      \
        }                                                                      \
      } else {                                                                 \
        _Pragma("unroll")                                                      \
        for (int r = 0; r < 4; ++r) p0[nf][r] = -INFINITY;                     \
      }                                                                        \
      {                                                                        \
        f32x4 z = {0.f, 0.f, 0.f, 0.f};                                        \
        z = __builtin_amdgcn_mfma_f32_16x16x32_bf16(k0_, qb10, z, 0, 0, 0);    \
        z = __builtin_amdgcn_mfma_f32_16x16x32_bf16(k1_, qb11, z, 0, 0, 0);    \
        _Pragma("unroll")                                                      \
        for (int r = 0; r < 4; ++r) {                                          \
          float sc = z[r];                                                     \
          if (DIAG && (nf * 16 + l4 * 4 + r) > (64 + w * 16 + l15)) sc = -INFINITY; \
          p1[nf][r] = sc;                                                      \
        }                                                                      \
      }                                                                        \
    }                                                                          \
    __builtin_amdgcn_s_setprio(0);                                             \
    SMAX8(p0, mrun0, lrun0, acc0);                                             \
    SMAX8(p1, mrun1, lrun1, acc1);                                             \
    PVBOTH(VC, 0, true);                                                       \
    PVBOTH(VC, 1, !(DIAG));                                                    \
    __syncthreads();                                                           \
  } while (0)

__global__ __launch_bounds__(256, 2) void k_flash(const ushort* __restrict__ qT,
                                                  const ushort* __restrict__ kT,
                                                  const ushort* __restrict__ vT,
                                                  ushort* __restrict__ AO) {
  __shared__ ushort Ks[2][128 * 64];
  __shared__ ushort Vs[2][64 * 128];
  __shared__ char Plds[4 * 4096];
  // Work-pairing decode: blocks 0..255 qt=15..8 desc, 256..511 qt=0..7 asc
  const int l = blockIdx.x;
  const int half = l >> 8, idx = l & 255;
  const int bh = (idx & 7) * 4 + ((idx >> 3) & 3);
  const int qt = half ? (idx >> 5) : (SEQ / 128 - 1) - (idx >> 5);
  const int tid = threadIdx.x, w = tid >> 6, lane = tid & 63;
  const int l15 = lane & 15, l4 = lane >> 4;
  const size_t hb = (size_t)bh * SEQ * DK;
  const size_t vbase = (size_t)bh * DK * SEQ;
  const int qrow0 = qt * 128 + w * 16;
  const int qrow1 = qrow0 + 64;
  const bf16x8 qb00 = *(const bf16x8*)(qT + hb + (size_t)(qrow0 + l15) * 64 + l4 * 8);
  const bf16x8 qb01 = *(const bf16x8*)(qT + hb + (size_t)(qrow0 + l15) * 64 + 32 + l4 * 8);
  const bf16x8 qb10 = *(const bf16x8*)(qT + hb + (size_t)(qrow1 + l15) * 64 + l4 * 8);
  const bf16x8 qb11 = *(const bf16x8*)(qT + hb + (size_t)(qrow1 + l15) * 64 + 32 + l4 * 8);
  f32x4 acc0[4] = {}, acc1[4] = {};
  float mrun0 = -INFINITY, lrun0 = 0.f, mrun1 = -INFINITY, lrun1 = 0.f;
  char* myP0 = (char*)Plds + w * 4096;
  char* myP1 = myP0 + 2048;
  const int swz = (l15 & 7) << 4;
  ushort* kc = &Ks[0][0]; ushort* vc = &Vs[0][0];
  ushort* kn = &Ks[1][0]; ushort* vn = &Vs[1][0];
  KSTAGE(kc, 0); VSTAGE(vc, 0);
  __syncthreads();
  for (int kt = 0; kt < qt; ++kt) {
    STEP(kc, vc, kn, vn, kt, false, true);
    ushort* t;
    t = kc; kc = kn; kn = t;
    t = vc; vc = vn; vn = t;
  }
  STEP(kc, vc, kn, vn, qt, true, false);
  lrun0 += __shfl_xor(lrun0, 16); lrun0 += __shfl_xor(lrun0, 32);
  lrun1 += __shfl_xor(lrun1, 16); lrun1 += __shfl_xor(lrun1, 32);
  const int b = bh >> 4, h = bh & 15;
  float lq0[4], lq1[4];
#pragma unroll
  for (int r = 0; r < 4; ++r) {
    lq0[r] = __shfl(lrun0, l4 * 4 + r);
    lq1[r] = __shfl(lrun1, l4 * 4 + r);
  }
#pragma unroll
  for (int r = 0; r < 4; ++r) {
    float inv0 = 1.f / lq0[r], inv1 = 1.f / lq1[r];
    int qr0 = qrow0 + l4 * 4 + r, qr1 = qrow1 + l4 * 4 + r;
#pragma unroll
    for (int df = 0; df < 4; ++df) {
      AO[(size_t)(b * SEQ + qr0) * DM + h * 64 + df * 16 + l15] = f2bf(acc0[df][r] * inv0);
      AO[(size_t)(b * SEQ + qr1) * DM + h * 64 + df * 16 + l15] = f2bf(acc1[df][r] * inv1);
    }
  }
}

extern "C" void kernel_launch(void* const* d_in, const int* in_sizes, int n_in,
                              void* d_out, int out_size, void* d_ws, size_t ws_size,
                              hipStream_t stream) {
  const float* Q = (const float*)d_in[0];
  const float* K = (const float*)d_in[1];
  const float* V = (const float*)d_in[2];
  const float* wq = (const float*)d_in[3];
  const float* wk = (const float*)d_in[4];
  const float* wv = (const float*)d_in[5];
  const float* wo = (const float*)d_in[6];
  float* out = (float*)d_out;
  char* ws = (char*)d_ws;

  ushort* XQ = (ushort*)(ws + 0);          // 8 MB each, XQ/XK/XV contiguous
  ushort* WQ = (ushort*)(ws + 25165824);   // 2 MB x4 (WQ,WK,WV,WO)
  ushort* qT = (ushort*)(ws + 33554432);   // 8 MB
  ushort* kT = (ushort*)(ws + 41943040);   // 8 MB
  ushort* vT = (ushort*)(ws + 50331648);   // 8 MB
  float* TAB = (float*)(ws + 58720256);    // 512 KB
  ushort* AO = XQ;                          // flash output (XQ consumed by gemm_qkv)

  P8 pin = {{Q, K, V, wq, wk, wv, wo}};
  k_prep<<<dim3(1024, 1, 7), 256, 0, stream>>>(pin, XQ, WQ, TAB);

  const float QSCALE = 0.125f * 1.4426950408889634f;  // 1/sqrt(dk) * log2(e)
  k_gemm_qkv<<<384, 512, 0, stream>>>(XQ, WQ, qT, kT, vT, TAB, QSCALE,
                                      BATCH * SEQ, DM, DM);

  k_flash<<<BH * (SEQ / 128), 256, 0, stream>>>(qT, kT, vT, AO);

  k_gemm_f<<<512, 256, 0, stream>>>(AO, WQ + 3 * DM * DM, out, BATCH * SEQ, DM, DM);
}

// Round 23
// 113.544 us; speedup vs baseline: 1.0772x; 1.0772x over previous
//
#include <hip/hip_runtime.h>

#define SEQ 2048
#define BATCH 2
#define DM 1024
#define NH 16
#define DK 64
#define BH (BATCH*NH)

typedef __attribute__((ext_vector_type(8))) short bf16x8;
typedef __attribute__((ext_vector_type(4))) float f32x4;

__device__ __forceinline__ ushort f2bf(float f) {
  union { float f; unsigned u; } v; v.f = f;
  unsigned r = (v.u + 0x7fffu + ((v.u >> 16) & 1u)) >> 16;
  return (ushort)r;
}
__device__ __forceinline__ float bf2f(ushort h) {
  union { unsigned u; float f; } v; v.u = ((unsigned)h) << 16;
  return v.f;
}
__device__ __forceinline__ unsigned cvtpk(float lo, float hi) {
  unsigned r;
  asm("v_cvt_pk_bf16_f32 %0, %1, %2" : "=v"(r) : "v"(lo), "v"(hi));
  return r;
}

// counted-vmcnt sync primitives (T4)
#define WAITV4 asm volatile("s_waitcnt vmcnt(4)" ::: "memory")
#define WAITV3 asm volatile("s_waitcnt vmcnt(3)" ::: "memory")
#define WAITV0 asm volatile("s_waitcnt vmcnt(0)" ::: "memory")
#define WAITL0 asm volatile("s_waitcnt lgkmcnt(0)" ::: "memory")
#define BARR() __builtin_amdgcn_s_barrier()

// ---------------- fused prep: X-cast (z<3), W-cast (z3..6), RoPE table -------
struct P8 { const float* p[7]; };
__global__ void k_prep(P8 in, ushort* __restrict__ xout, ushort* __restrict__ wout,
                       float* __restrict__ tab) {
  const int z = blockIdx.z;
  const float* src = in.p[z];
  ushort* dst;
  int n4;
  if (z < 3) {
    dst = xout + (size_t)z * (BATCH * SEQ * DM);
    n4 = BATCH * SEQ * DM / 4;
  } else {
    dst = wout + (size_t)(z - 3) * (DM * DM);
    n4 = DM * DM / 4;
  }
  int i = blockIdx.x * blockDim.x + threadIdx.x;
  int st = gridDim.x * blockDim.x;
  for (; i < n4; i += st) {
    float4 v = reinterpret_cast<const float4*>(src)[i];
    ushort4 o;
    o.x = f2bf(v.x); o.y = f2bf(v.y); o.z = f2bf(v.z); o.w = f2bf(v.w);
    reinterpret_cast<ushort4*>(dst)[i] = o;
  }
  if (z == 3 && blockIdx.x < 256) {
    int id = blockIdx.x * 256 + threadIdx.x;   // < 65536 = SEQ*32
    int s = id >> 5, ii = id & 31;
    float inv = powf(10000.f, -(float)ii / 32.f);
    float ang = (float)s * inv;
    float sn, cs;
    sincosf(ang, &sn, &cs);
    tab[id * 2] = cs;
    tab[id * 2 + 1] = sn;
  }
}

// ---------------- async global->LDS 16B ----------------
__device__ __forceinline__ void gll16(const void* g, void* l) {
  __builtin_amdgcn_global_load_lds((const __attribute__((address_space(1))) void*)g,
                                   (__attribute__((address_space(3))) void*)l, 16, 0, 0);
}

// chunk-XOR swizzled fragment read: [256 rows][32 bf16], row stride 64 B
#define AFRAG(AS_, row_)                                                       \
  (*(const bf16x8*)((const char*)(AS_) + (row_) * 64 + ((((l4) ^ (((row_) >> 1) & 3)) & 3) * 16)))

// ---------------- QKV GEMM: 256x256, 8-phase fine-interleaved (T3+T4) --------
#define STG(DST, SRCB, kk_) do {                                               \
    _Pragma("unroll")                                                          \
    for (int i_ = 0; i_ < 2; ++i_) {                                           \
      int tt_ = i_ * 512 + tid;                                                \
      int row_ = tt_ >> 2, c_ = (tt_ & 3) ^ ((row_ >> 1) & 3);                 \
      gll16((SRCB) + (size_t)row_ * K + (kk_) + c_ * 8,                        \
            (void*)((char*)(DST) + tt_ * 16));                                 \
    }                                                                          \
  } while (0)

// one phase: af reads for mh; optional bfr reload; stage stmt; MFMA quadrant
#define PH(ABUF, BBUF, MH, LOADB, ...) do {                                    \
    _Pragma("unroll")                                                          \
    for (int i = 0; i < 4; ++i)                                                \
      af[i] = AFRAG(ABUF, wr * 128 + (MH) * 64 + i * 16 + l15);                \
    if (LOADB) {                                                               \
      _Pragma("unroll")                                                        \
      for (int i = 0; i < 4; ++i)                                              \
        bfr[i] = AFRAG(BBUF, wc * 64 + i * 16 + l15);                          \
    }                                                                          \
    __VA_ARGS__;                                                               \
    WAITL0;                                                                    \
    __builtin_amdgcn_s_setprio(1);                                             \
    _Pragma("unroll")                                                          \
    for (int i = 0; i < 4; ++i)                                                \
      _Pragma("unroll")                                                        \
      for (int ni = 0; ni < 4; ++ni)                                           \
        acc[(MH) * 4 + i][ni] = __builtin_amdgcn_mfma_f32_16x16x32_bf16(       \
            af[i], bfr[ni], acc[(MH) * 4 + i][ni], 0, 0, 0);                   \
    __builtin_amdgcn_s_setprio(0);                                             \
  } while (0)

// grid: flat 192 = 8(mlo) x 4(nb) x 2(mhi) x 3(z); id%8==mlo -> XCD-local A.
__global__ __launch_bounds__(512, 1) void k_gemm_qkv(const ushort* __restrict__ A0,
                                                     const ushort* __restrict__ Bw0,
                                                     ushort* __restrict__ qT,
                                                     ushort* __restrict__ kT,
                                                     ushort* __restrict__ vT,
                                                     const float* __restrict__ tab,
                                                     float qscale, int M, int N, int K) {
  const int id = blockIdx.x;
  const int mlo = id & 7, nb = (id >> 3) & 3, mhi = (id >> 5) & 1, z = id >> 6;
  const int m0 = (mhi * 8 + mlo) * 256, n0 = nb * 256;
  const ushort* Abase = A0 + (size_t)z * ((size_t)M * K) + (size_t)m0 * K;
  const ushort* Bbase = Bw0 + (size_t)z * ((size_t)N * K) + (size_t)n0 * K;
  __shared__ ushort As[2][2][256 * 32];   // [dbuf][khalf] 16 KB each
  __shared__ ushort Bs[2][2][256 * 32];
  const int tid = threadIdx.x;
  const int w = tid >> 6, lane = tid & 63;
  const int l15 = lane & 15, l4 = lane >> 4;
  const int wr = w >> 2, wc = w & 3;       // 2 x 4 waves -> per-wave 128x64
  f32x4 acc[8][4] = {};
  bf16x8 af[4], bfr[4];
  // prologue: tile 0 (k 0..64) -> dbuf0
  STG(As[0][0], Abase, 0);
  STG(Bs[0][0], Bbase, 0);
  STG(As[0][1], Abase, 32);
  STG(Bs[0][1], Bbase, 32);
  for (int i = 0; i < 8; ++i) {
    const int kb = i * 128;
    const bool st = (i < 7);
    WAITV4; BARR();
    PH(As[0][0], Bs[0][0], 0, 1, STG(As[1][0], Abase, kb + 64));
    BARR();
    PH(As[0][0], Bs[0][0], 1, 0, STG(Bs[1][0], Bbase, kb + 64));
    WAITV4; BARR();
    PH(As[0][1], Bs[0][1], 0, 1, STG(As[1][1], Abase, kb + 96));
    BARR();
    PH(As[0][1], Bs[0][1], 1, 0, STG(Bs[1][1], Bbase, kb + 96));
    WAITV4; BARR();
    PH(As[1][0], Bs[1][0], 0, 1, if (st) STG(As[0][0], Abase, kb + 128));
    BARR();
    PH(As[1][0], Bs[1][0], 1, 0, if (st) STG(Bs[0][0], Bbase, kb + 128));
    if (st) { WAITV4; } else { WAITV0; }
    BARR();
    PH(As[1][1], Bs[1][1], 0, 1, if (st) STG(As[0][1], Abase, kb + 160));
    BARR();
    PH(As[1][1], Bs[1][1], 1, 0, if (st) STG(Bs[0][1], Bbase, kb + 160));
  }
  // epilogues
  if (z == 2) {
#pragma unroll
    for (int mi = 0; mi < 8; ++mi)
#pragma unroll
      for (int ni = 0; ni < 4; ++ni) {
        int row = m0 + wr * 128 + mi * 16 + l4 * 4;
        int col = n0 + wc * 64 + ni * 16 + l15;
        int bh2 = (row >> 11) * 16 + (col >> 6);
        int d = col & 63, s = row & (SEQ - 1);
        uint2 pk;
        pk.x = cvtpk(acc[mi][ni][0], acc[mi][ni][1]);
        pk.y = cvtpk(acc[mi][ni][2], acc[mi][ni][3]);
        *(uint2*)(vT + ((size_t)bh2 * 64 + d) * SEQ + s) = pk;
      }
  } else {
    const float scale = (z == 0) ? qscale : 1.0f;
    ushort* T = (z == 0) ? qT : kT;
    const bool odd = (l15 & 1);
#pragma unroll
    for (int mi = 0; mi < 8; ++mi)
#pragma unroll
      for (int ni = 0; ni < 4; ++ni)
#pragma unroll
        for (int r = 0; r < 4; ++r) {
          int row = m0 + wr * 128 + mi * 16 + l4 * 4 + r;
          int col = n0 + wc * 64 + ni * 16 + l15;
          float v = acc[mi][ni][r];
          float pv = __shfl_xor(v, 1);
          int s = row & (SEQ - 1);
          int d = col & 63;
          float2 cs = *(const float2*)(tab + ((size_t)s * 32 + (d >> 1)) * 2);
          float xe = odd ? pv : v, xo = odd ? v : pv;
          float outv = (odd ? (xe * cs.y + xo * cs.x) : (xe * cs.x - xo * cs.y)) * scale;
          int bh2 = (row >> 11) * 16 + (col >> 6);
          T[((size_t)bh2 * SEQ + s) * 64 + d] = f2bf(outv);
        }
  }
}

// ---------------- final GEMM: counted-vmcnt 2-deep pipeline, fp32 out --------
#define FSTAGE(AD, BD, kk_) do {                                               \
    gll16(A + (size_t)(m0 + srow) * K + (kk_) + scol, (void*)((AD) + w * 512));\
    gll16(Bw + (size_t)(n0 + srow) * K + (kk_) + scol, (void*)((BD) + w * 512));\
    gll16(Bw + (size_t)(n0 + 64 + srow) * K + (kk_) + scol, (void*)((BD) + 2048 + w * 512)); \
  } while (0)

#define FCOMP(AS_, BS_) do {                                                   \
    bf16x8 aff[2], bff[4];                                                     \
    _Pragma("unroll")                                                          \
    for (int i = 0; i < 2; ++i)                                                \
      aff[i] = *(const bf16x8*)((AS_) + (wr * 32 + i * 16 + l15) * 32 + l4 * 8);\
    _Pragma("unroll")                                                          \
    for (int i = 0; i < 4; ++i)                                                \
      bff[i] = *(const bf16x8*)((BS_) + (wc * 64 + i * 16 + l15) * 32 + l4 * 8);\
    _Pragma("unroll")                                                          \
    for (int mi = 0; mi < 2; ++mi)                                             \
      _Pragma("unroll")                                                        \
      for (int ni = 0; ni < 4; ++ni)                                           \
        acc[mi][ni] = __builtin_amdgcn_mfma_f32_16x16x32_bf16(aff[mi], bff[ni], acc[mi][ni], 0, 0, 0); \
  } while (0)

__global__ __launch_bounds__(256) void k_gemm_f(const ushort* __restrict__ A,
                                                const ushort* __restrict__ Bw,
                                                float* __restrict__ C, int M, int N, int K) {
  const int id = blockIdx.x;
  const int mlo = id & 7, nb = (id >> 3) & 7, mhi = id >> 6;
  const int m0 = (mhi * 8 + mlo) * 64, n0 = nb * 128;
  __shared__ ushort As0[64 * 32], Bs0[128 * 32];
  __shared__ ushort As1[64 * 32], Bs1[128 * 32];
  const int tid = threadIdx.x;
  const int w = tid >> 6, lane = tid & 63;
  const int l15 = lane & 15, l4 = lane >> 4;
  const int wr = w >> 1, wc = w & 1;
  const int srow = tid >> 2, scol = (tid & 3) * 8;
  f32x4 acc[2][4] = {};
  FSTAGE(As0, Bs0, 0);
  FSTAGE(As1, Bs1, 32);
  for (int kk = 0; kk < K - 64; kk += 64) {
    WAITV3; BARR();
    FCOMP(As0, Bs0);
    WAITL0; BARR();
    FSTAGE(As0, Bs0, kk + 64);
    WAITV3; BARR();
    FCOMP(As1, Bs1);
    WAITL0; BARR();
    if (kk + 96 < K) FSTAGE(As1, Bs1, kk + 96);
  }
  WAITV3; BARR();
  FCOMP(As0, Bs0);
  WAITV0; BARR();
  FCOMP(As1, Bs1);
#pragma unroll
  for (int mi = 0; mi < 2; ++mi)
#pragma unroll
    for (int ni = 0; ni < 4; ++ni)
#pragma unroll
      for (int r = 0; r < 4; ++r) {
        int row = m0 + wr * 32 + mi * 16 + l4 * 4 + r;
        int col = n0 + wc * 64 + ni * 16 + l15;
        C[(size_t)row * N + col] = acc[mi][ni][r];
      }
}

// ---------------- causal flash attention: QBLK=128, KVBLK=128 ----------------
#define KSTAGE(DST, kt_) do {                                                  \
    const ushort* kb_ = kT + hb + (size_t)(kt_) * 8192;                        \
    _Pragma("unroll")                                                          \
    for (int i_ = 0; i_ < 4; ++i_) {                                           \
      int tt_ = i_ * 256 + tid;                                                \
      int row_ = tt_ >> 3, c_ = (tt_ & 7) ^ (row_ & 7);                        \
      gll16(kb_ + (size_t)row_ * 64 + c_ * 8,                                  \
            (void*)((char*)(DST) + (i_ * 256 + w * 64) * 16));                 \
    }                                                                          \
  } while (0)

#define VSTAGE(DST, kt_) do {                                                  \
    const ushort* vb_ = vT + vbase + (size_t)(kt_) * 128;                      \
    _Pragma("unroll")                                                          \
    for (int i_ = 0; i_ < 4; ++i_) {                                           \
      int tt_ = i_ * 256 + tid;                                                \
      int row_ = tt_ >> 4, c_ = (tt_ & 15) ^ (row_ & 15);                      \
      gll16(vb_ + (size_t)row_ * SEQ + c_ * 8,                                 \
            (void*)((char*)(DST) + (i_ * 256 + w * 64) * 16));                 \
    }                                                                          \
  } while (0)

#define FRK(BASE, row_, cidx)                                                  \
  (*(const bf16x8*)((const char*)(BASE) + (row_) * 128 + ((((cidx) ^ ((row_) & 7)) & 7) * 16)))
#define FRV(BASE, row_, cidx)                                                  \
  (*(const bf16x8*)((const char*)(BASE) + (row_) * 256 + ((((cidx) ^ ((row_) & 15)) & 15) * 16)))

#define SMAX8(P, MRUN, LRUN, ACC) do {                                         \
    float mx = P[0][0];                                                        \
    _Pragma("unroll")                                                          \
    for (int nf = 0; nf < 8; ++nf)                                             \
      _Pragma("unroll")                                                        \
      for (int r = 0; r < 4; ++r) mx = fmaxf(mx, P[nf][r]);                    \
    mx = fmaxf(mx, __shfl_xor(mx, 16));                                        \
    mx = fmaxf(mx, __shfl_xor(mx, 32));                                        \
    if (!__all(mx <= MRUN)) {                                                  \
      const float mn = fmaxf(MRUN, mx);                                        \
      const float so = __builtin_amdgcn_exp2f(MRUN - mn);                      \
      float soq[4];                                                            \
      _Pragma("unroll")                                                        \
      for (int r = 0; r < 4; ++r) soq[r] = __shfl(so, l4 * 4 + r);             \
      _Pragma("unroll")                                                        \
      for (int df = 0; df < 4; ++df)                                           \
        _Pragma("unroll")                                                      \
        for (int r = 0; r < 4; ++r) ACC[df][r] *= soq[r];                      \
      LRUN *= so;                                                              \
      MRUN = mn;                                                               \
    }                                                                          \
    float rs = 0.f;                                                            \
    _Pragma("unroll")                                                          \
    for (int nf = 0; nf < 8; ++nf) {                                           \
      float e0 = __builtin_amdgcn_exp2f(P[nf][0] - MRUN);                      \
      float e1 = __builtin_amdgcn_exp2f(P[nf][1] - MRUN);                      \
      float e2 = __builtin_amdgcn_exp2f(P[nf][2] - MRUN);                      \
      float e3 = __builtin_amdgcn_exp2f(P[nf][3] - MRUN);                      \
      P[nf][0] = e0; P[nf][1] = e1; P[nf][2] = e2; P[nf][3] = e3;              \
      rs += (e0 + e1) + (e2 + e3);                                             \
    }                                                                          \
    LRUN += rs;                                                                \
  } while (0)

// PV for one 64-k half H, BOTH strips sharing the V-fragment reads.
#define PVBOTH(VC, H, DO0) do {                                                \
    if (DO0) {                                                                 \
      _Pragma("unroll")                                                        \
      for (int i = 0; i < 4; ++i) {                                            \
        uint2 pk;                                                              \
        pk.x = cvtpk(p0[(H) * 4 + i][0], p0[(H) * 4 + i][1]);                  \
        pk.y = cvtpk(p0[(H) * 4 + i][2], p0[(H) * 4 + i][3]);                  \
        *(uint2*)(myP0 + ((l15 * 128 + i * 32 + l4 * 8) ^ swz)) = pk;          \
      }                                                                        \
    }                                                                          \
    _Pragma("unroll")                                                          \
    for (int i = 0; i < 4; ++i) {                                              \
      uint2 pk;                                                                \
      pk.x = cvtpk(p1[(H) * 4 + i][0], p1[(H) * 4 + i][1]);                    \
      pk.y = cvtpk(p1[(H) * 4 + i][2], p1[(H) * 4 + i][3]);                    \
      *(uint2*)(myP1 + ((l15 * 128 + i * 32 + l4 * 8) ^ swz)) = pk;            \
    }                                                                          \
    bf16x8 pa00, pa01;                                                         \
    if (DO0) {                                                                 \
      pa00 = *(const bf16x8*)(myP0 + ((l15 * 128 + l4 * 16) ^ swz));           \
      pa01 = *(const bf16x8*)(myP0 + ((l15 * 128 + 64 + l4 * 16) ^ swz));      \
    }                                                                          \
    const bf16x8 pa10 = *(const bf16x8*)(myP1 + ((l15 * 128 + l4 * 16) ^ swz));\
    const bf16x8 pa11 = *(const bf16x8*)(myP1 + ((l15 * 128 + 64 + l4 * 16) ^ swz));\
    __builtin_amdgcn_s_setprio(1);                                             \
    _Pragma("unroll")                                                          \
    for (int df = 0; df < 4; ++df) {                                           \
      bf16x8 v0_ = FRV(VC, df * 16 + l15, (H) * 8 + l4);                       \
      bf16x8 v1_ = FRV(VC, df * 16 + l15, (H) * 8 + l4 + 4);                   \
      if (DO0) {                                                               \
        acc0[df] = __builtin_amdgcn_mfma_f32_16x16x32_bf16(pa00, v0_, acc0[df], 0, 0, 0); \
        acc0[df] = __builtin_amdgcn_mfma_f32_16x16x32_bf16(pa01, v1_, acc0[df], 0, 0, 0); \
      }                                                                        \
      acc1[df] = __builtin_amdgcn_mfma_f32_16x16x32_bf16(pa10, v0_, acc1[df], 0, 0, 0); \
      acc1[df] = __builtin_amdgcn_mfma_f32_16x16x32_bf16(pa11, v1_, acc1[df], 0, 0, 0); \
    }                                                                          \
    __builtin_amdgcn_s_setprio(0);                                             \
  } while (0)

#define STEP(KC, VC, KN, VN, kt_, DIAG, PREF) do {                             \
    if (PREF) { KSTAGE(KN, (kt_) + 1); VSTAGE(VN, (kt_) + 1); }                \
    float p0[8][4], p1[8][4];                                                  \
    __builtin_amdgcn_s_setprio(1);                                             \
    _Pragma("unroll")                                                          \
    for (int nf = 0; nf < 8; ++nf) {                                           \
      bf16x8 k0_ = FRK(KC, nf * 16 + l15, l4);                                 \
      bf16x8 k1_ = FRK(KC, nf * 16 + l15, l4 + 4);                             \
      if (!(DIAG) || nf < 4) {                                                 \
        f32x4 z = {0.f, 0.f, 0.f, 0.f};                                        \
        z = __builtin_amdgcn_mfma_f32_16x16x32_bf16(k0_, qb00, z, 0, 0, 0);    \
        z = __builtin_amdgcn_mfma_f32_16x16x32_bf16(k1_, qb01, z, 0, 0, 0);    \
        _Pragma("unroll")                                                      \
        for (int r = 0; r < 4; ++r) {                                          \
          float sc = z[r];                                                     \
          if (DIAG && (nf * 16 + l4 * 4 + r) > (w * 16 + l15)) sc = -INFINITY; \
          p0[nf][r] = sc;                                                      \
        }                                                                      \
      } else {                                                                 \
        _Pragma("unroll")                                                      \
        for (int r = 0; r < 4; ++r) p0[nf][r] = -INFINITY;                     \
      }                                                                        \
      {                                                                        \
        f32x4 z = {0.f, 0.f, 0.f, 0.f};                                        \
        z = __builtin_amdgcn_mfma_f32_16x16x32_bf16(k0_, qb10, z, 0, 0, 0);    \
        z = __builtin_amdgcn_mfma_f32_16x16x32_bf16(k1_, qb11, z, 0, 0, 0);    \
        _Pragma("unroll")                                                      \
        for (int r = 0; r < 4; ++r) {                                          \
          float sc = z[r];                                                     \
          if (DIAG && (nf * 16 + l4 * 4 + r) > (64 + w * 16 + l15)) sc = -INFINITY; \
          p1[nf][r] = sc;                                                      \
        }                                                                      \
      }                                                                        \
    }                                                                          \
    __builtin_amdgcn_s_setprio(0);                                             \
    SMAX8(p0, mrun0, lrun0, acc0);                                             \
    SMAX8(p1, mrun1, lrun1, acc1);                                             \
    PVBOTH(VC, 0, true);                                                       \
    PVBOTH(VC, 1, !(DIAG));                                                    \
    __syncthreads();                                                           \
  } while (0)

__global__ __launch_bounds__(256, 2) void k_flash(const ushort* __restrict__ qT,
                                                  const ushort* __restrict__ kT,
                                                  const ushort* __restrict__ vT,
                                                  ushort* __restrict__ AO) {
  __shared__ ushort Ks[2][128 * 64];
  __shared__ ushort Vs[2][64 * 128];
  __shared__ char Plds[4 * 4096];
  // Work-pairing decode: blocks 0..255 qt=15..8 desc, 256..511 qt=0..7 asc
  const int l = blockIdx.x;
  const int half = l >> 8, idx = l & 255;
  const int bh = (idx & 7) * 4 + ((idx >> 3) & 3);
  const int qt = half ? (idx >> 5) : (SEQ / 128 - 1) - (idx >> 5);
  const int tid = threadIdx.x, w = tid >> 6, lane = tid & 63;
  const int l15 = lane & 15, l4 = lane >> 4;
  const size_t hb = (size_t)bh * SEQ * DK;
  const size_t vbase = (size_t)bh * DK * SEQ;
  const int qrow0 = qt * 128 + w * 16;
  const int qrow1 = qrow0 + 64;
  const bf16x8 qb00 = *(const bf16x8*)(qT + hb + (size_t)(qrow0 + l15) * 64 + l4 * 8);
  const bf16x8 qb01 = *(const bf16x8*)(qT + hb + (size_t)(qrow0 + l15) * 64 + 32 + l4 * 8);
  const bf16x8 qb10 = *(const bf16x8*)(qT + hb + (size_t)(qrow1 + l15) * 64 + l4 * 8);
  const bf16x8 qb11 = *(const bf16x8*)(qT + hb + (size_t)(qrow1 + l15) * 64 + 32 + l4 * 8);
  f32x4 acc0[4] = {}, acc1[4] = {};
  float mrun0 = -INFINITY, lrun0 = 0.f, mrun1 = -INFINITY, lrun1 = 0.f;
  char* myP0 = (char*)Plds + w * 4096;
  char* myP1 = myP0 + 2048;
  const int swz = (l15 & 7) << 4;
  ushort* kc = &Ks[0][0]; ushort* vc = &Vs[0][0];
  ushort* kn = &Ks[1][0]; ushort* vn = &Vs[1][0];
  KSTAGE(kc, 0); VSTAGE(vc, 0);
  __syncthreads();
  for (int kt = 0; kt < qt; ++kt) {
    STEP(kc, vc, kn, vn, kt, false, true);
    ushort* t;
    t = kc; kc = kn; kn = t;
    t = vc; vc = vn; vn = t;
  }
  STEP(kc, vc, kn, vn, qt, true, false);
  lrun0 += __shfl_xor(lrun0, 16); lrun0 += __shfl_xor(lrun0, 32);
  lrun1 += __shfl_xor(lrun1, 16); lrun1 += __shfl_xor(lrun1, 32);
  const int b = bh >> 4, h = bh & 15;
  float lq0[4], lq1[4];
#pragma unroll
  for (int r = 0; r < 4; ++r) {
    lq0[r] = __shfl(lrun0, l4 * 4 + r);
    lq1[r] = __shfl(lrun1, l4 * 4 + r);
  }
#pragma unroll
  for (int r = 0; r < 4; ++r) {
    float inv0 = 1.f / lq0[r], inv1 = 1.f / lq1[r];
    int qr0 = qrow0 + l4 * 4 + r, qr1 = qrow1 + l4 * 4 + r;
#pragma unroll
    for (int df = 0; df < 4; ++df) {
      AO[(size_t)(b * SEQ + qr0) * DM + h * 64 + df * 16 + l15] = f2bf(acc0[df][r] * inv0);
      AO[(size_t)(b * SEQ + qr1) * DM + h * 64 + df * 16 + l15] = f2bf(acc1[df][r] * inv1);
    }
  }
}

extern "C" void kernel_launch(void* const* d_in, const int* in_sizes, int n_in,
                              void* d_out, int out_size, void* d_ws, size_t ws_size,
                              hipStream_t stream) {
  const float* Q = (const float*)d_in[0];
  const float* K = (const float*)d_in[1];
  const float* V = (const float*)d_in[2];
  const float* wq = (const float*)d_in[3];
  const float* wk = (const float*)d_in[4];
  const float* wv = (const float*)d_in[5];
  const float* wo = (const float*)d_in[6];
  float* out = (float*)d_out;
  char* ws = (char*)d_ws;

  ushort* XQ = (ushort*)(ws + 0);          // 8 MB each, XQ/XK/XV contiguous
  ushort* WQ = (ushort*)(ws + 25165824);   // 2 MB x4 (WQ,WK,WV,WO)
  ushort* qT = (ushort*)(ws + 33554432);   // 8 MB
  ushort* kT = (ushort*)(ws + 41943040);   // 8 MB
  ushort* vT = (ushort*)(ws + 50331648);   // 8 MB
  float* TAB = (float*)(ws + 58720256);    // 512 KB
  ushort* AO = XQ;                          // flash output (XQ consumed by gemm_qkv)

  P8 pin = {{Q, K, V, wq, wk, wv, wo}};
  k_prep<<<dim3(1024, 1, 7), 256, 0, stream>>>(pin, XQ, WQ, TAB);

  const float QSCALE = 0.125f * 1.4426950408889634f;  // 1/sqrt(dk) * log2(e)
  k_gemm_qkv<<<192, 512, 0, stream>>>(XQ, WQ, qT, kT, vT, TAB, QSCALE,
                                      BATCH * SEQ, DM, DM);

  k_flash<<<BH * (SEQ / 128), 256, 0, stream>>>(qT, kT, vT, AO);

  k_gemm_f<<<512, 256, 0, stream>>>(AO, WQ + 3 * DM * DM, out, BATCH * SEQ, DM, DM);
}